// Round 7
// baseline (2589.004 us; speedup 1.0000x reference)
//
#include <hip/hip_runtime.h>
#include <stdint.h>

#define NB 512   // batch
#define NN 128   // nodes
#define NT 336   // timesteps
#define NH 32    // hidden
#define NG 128   // 4*H

typedef short bf16x8 __attribute__((ext_vector_type(8)));
typedef float f32x4  __attribute__((ext_vector_type(4)));
typedef float f32x2  __attribute__((ext_vector_type(2)));
typedef float f32v4  __attribute__((ext_vector_type(4)));

#define LOG2E 1.4426950408889634f
#define KNEG  (-2.0f * LOG2E)   // tanh-arg scale, folded into c-state

__device__ __forceinline__ f32x2 exp2v(f32x2 v) {
  f32x2 r; r.x = __builtin_amdgcn_exp2f(v.x); r.y = __builtin_amdgcn_exp2f(v.y); return r;
}
__device__ __forceinline__ f32x2 rcpv(f32x2 v) {
  f32x2 r; r.x = __builtin_amdgcn_rcpf(v.x); r.y = __builtin_amdgcn_rcpf(v.y); return r;
}
// float -> bf16, round-to-nearest (ties away): add + hi16 store
__device__ __forceinline__ short f2bf(float f) {
  unsigned u = __builtin_bit_cast(unsigned, f) + 0x8000u;
  return (short)(u >> 16);
}

// Fused LSTM cell for a pair of batch rows (packed f32x2).
// Gate pre-activations arrive pre-scaled: i,f,o by -log2e; g by -2log2e.
// c-state is stored SCALED by KNEG (= -2log2e): the tanh exp2-arg IS the state.
//   cS' = [cS*Ai*Au + nuk*Af] / (Af*Ai*Au)   -- single rcp   (nuk = KNEG*(1-u'))
//   h   = (1-v) / (Ao*(1+v)),  v = exp2(min(cS',80))  -- single rcp
// BIAS=true folds bias multiplicatively; ebg = e^{b'_g}, kng = -KNEG*ebg precomputed.
template<bool BIAS>
__device__ __forceinline__ f32x2 cell_pair(f32x2 gi, f32x2 gf, f32x2 gg, f32x2 go,
                                           f32x2& cst, float ebi, float ebf,
                                           float ebg, float kng, float ebo) {
  f32x2 wi = exp2v(gi), wf = exp2v(gf), uu = exp2v(gg), wo = exp2v(go);
  f32x2 Ai, Af, Au, Ao, nuk;
  if (BIAS) {
    Ai  = wi * ebi + 1.0f;          // v_pk_fma_f32
    Af  = wf * ebf + 1.0f;
    Au  = uu * ebg + 1.0f;
    Ao  = wo * ebo + 1.0f;
    nuk = uu * kng + KNEG;          // KNEG*(1 - uu*ebg)
  } else {
    Ai  = wi + 1.0f; Af = wf + 1.0f; Au = uu + 1.0f; Ao = wo + 1.0f;
    nuk = uu * (-KNEG) + KNEG;      // KNEG*(1-uu)
  }
  f32x2 P  = Ai * Au;
  f32x2 N  = cst * P + nuk * Af;
  f32x2 cS = N * rcpv(Af * P);      // = KNEG * c_new
  cst = cS;
  f32x2 sarg = cS;
  // guard: c very negative -> v=inf -> inf/inf NaN. Clamped value still gives -sigma(o).
  sarg.x = fminf(sarg.x, 80.0f);
  sarg.y = fminf(sarg.y, 80.0f);
  f32x2 vv = exp2v(sarg);
  f32x2 hh = (1.0f - vv) * rcpv(Ao * (vv + 1.0f));
  return hh;
}

// One wave handles (node n, 16 batch rows). Block = 4 waves = 64 rows of one node.
// Grid = 128 nodes * 8 row-groups = 1024 blocks.
// launch_bounds(256,2): 2 blocks/CU -- (256,3) SPILLS (r5: 3.4x slower, 9.7GB scratch).
__global__ __launch_bounds__(256, 2) void lstm_kernel(
    const float* __restrict__ x,
    const float* __restrict__ Wih0,
    const float* __restrict__ Whh0,
    const float* __restrict__ b0,
    const float* __restrict__ Wih1,
    const float* __restrict__ Whh1,
    const float* __restrict__ b1,
    const float* __restrict__ Wfc,
    const float* __restrict__ bfc,
    float* __restrict__ out)
{
  const int tid  = threadIdx.x;
  const int wave = tid >> 6;
  const int lane = tid & 63;
  const int c    = lane & 15;   // tile column (gate-within-tile / A-row)
  const int q    = lane >> 4;   // quad
  const int n    = blockIdx.x >> 3;
  const int m0   = ((blockIdx.x & 7) * 4 + wave) * 16;  // batch row base of this wave

  // Per-wave private LDS: 2 buffers of 16 rows x 40 bf16 (stride 40 -> 80B rows,
  // 16B-aligned b128 reads). No cross-wave sharing -> no barriers.
  __shared__ short lds[4 * 2 * 16 * 40];
  short* my0 = lds + wave * (2 * 16 * 40);
  short* my1 = my0 + 16 * 40;

  // Per-tile folded scale: tiles 0-3 = i,f (sigmoid, -log2e); 4-5 = g (tanh, -2log2e);
  // 6-7 = o (sigmoid, -log2e).
  const float sc_tab[8] = {-LOG2E, -LOG2E, -LOG2E, -LOG2E,
                           -2.0f * LOG2E, -2.0f * LOG2E, -LOG2E, -LOG2E};

  // ---- Load weight B-fragments (held for the whole T loop) ----
  // B-frag (K x N = 32 x 16): lane holds B[k = q*8+j][nn = c] = sc * W[tau*16+c][q*8+j]
  bf16x8 wb0[8], wb1[8], wb2[8];
  {
    const float* pW0 = Whh0 + n * (NG * NH);
    const float* pW1 = Wih1 + n * (NG * NH);
    const float* pW2 = Whh1 + n * (NG * NH);
#pragma unroll
    for (int tau = 0; tau < 8; ++tau) {
      int off = (tau * 16 + c) * NH + q * 8;
      float sc = sc_tab[tau];
#pragma unroll
      for (int j = 0; j < 8; ++j) {
        wb0[tau][j] = f2bf(sc * pW0[off + j]);
        wb1[tau][j] = f2bf(sc * pW1[off + j]);
        wb2[tau][j] = f2bf(sc * pW2[off + j]);
      }
    }
  }
  // Register-class steering: weights are read-only MFMA srcs -> park them in AGPRs,
  // freeing ~96 arch VGPRs so accumulators + cell-math temps stay in VGPRs
  // (goal: zero v_accvgpr_read/write in the hot loop).
#pragma unroll
  for (int tau = 0; tau < 8; ++tau) {
    asm volatile("" : "+a"(wb0[tau]));
    asm volatile("" : "+a"(wb1[tau]));
    asm volatile("" : "+a"(wb2[tau]));
  }

  // Per-lane gate constants: g = tau*16 + c.
  // Layer 0: additive (folded into MFMA C init). Layer 1: multiplicative e^{sc*b}.
  float b0g[8], eb1[8], wi0g[8];
#pragma unroll
  for (int tau = 0; tau < 8; ++tau) {
    int g = tau * 16 + c;
    float sc = sc_tab[tau];
    b0g[tau]  = sc * b0[n * NG + g];
    eb1[tau]  = __builtin_amdgcn_exp2f(sc * b1[n * NG + g]);
    wi0g[tau] = sc * Wih0[n * NG + g];   // W_ih0[n, g, 0]
  }
  const float kng4 = (-KNEG) * eb1[4];   // for g-gate tiles of layer 1
  const float kng5 = (-KNEG) * eb1[5];
  const float wfc0 = Wfc[n * NH + c];
  const float wfc1 = Wfc[n * NH + 16 + c];

  // x row pointers for the 4 batch rows this lane's quad covers (m = q*4 + r)
  const float* px0 = x + ((size_t)(m0 + q * 4 + 0) * NN + n) * NT;
  const float* px1 = x + ((size_t)(m0 + q * 4 + 1) * NN + n) * NT;
  const float* px2 = x + ((size_t)(m0 + q * 4 + 2) * NN + n) * NT;
  const float* px3 = x + ((size_t)(m0 + q * 4 + 3) * NN + n) * NT;

  // Recurrent state. a0/a1: A-frags of h0/h1 (bf16). c-state (scaled by KNEG) packed f32x2,
  // indexed [tu][pair] where pair p covers rows {2p, 2p+1}.
  bf16x8 a0 = {0,0,0,0,0,0,0,0};
  bf16x8 a1 = {0,0,0,0,0,0,0,0};
  f32x2 c0p[2][2], c1p[2][2];
#pragma unroll
  for (int tu = 0; tu < 2; ++tu)
#pragma unroll
    for (int p = 0; p < 2; ++p) {
      c0p[tu][p] = (f32x2){0.f, 0.f};
      c1p[tu][p] = (f32x2){0.f, 0.f};
    }

  const f32x4 zero4 = {0.f, 0.f, 0.f, 0.f};  // shared MFMA C for layer-1 init

#pragma unroll 1
  for (int t4 = 0; t4 < NT / 4; ++t4) {
    // 4 timesteps of x per batch row, vectorized load (r4 structure; prefetch regressed r6)
    f32v4 xr0 = *(const f32v4*)(px0 + t4 * 4);
    f32v4 xr1 = *(const f32v4*)(px1 + t4 * 4);
    f32v4 xr2 = *(const f32v4*)(px2 + t4 * 4);
    f32v4 xr3 = *(const f32v4*)(px3 + t4 * 4);

#pragma unroll
    for (int ts = 0; ts < 4; ++ts) {
      f32x2 x01 = {xr0[ts], xr1[ts]};
      f32x2 x23 = {xr2[ts], xr3[ts]};

      // ---- Layer 0: gates' = sc*(x*Wi0 + b0) + h0_prev @ (sc*W_hh0)^T ----
      f32x4 acc[8];
#pragma unroll
      for (int tau = 0; tau < 8; ++tau) {
        f32x2 w2 = {wi0g[tau], wi0g[tau]};
        f32x2 b2 = {b0g[tau], b0g[tau]};
        f32x2 lo = x01 * w2 + b2;   // v_pk_fma_f32
        f32x2 hi = x23 * w2 + b2;
        acc[tau] = (f32x4){lo.x, lo.y, hi.x, hi.y};
      }
#pragma unroll
      for (int tau = 0; tau < 8; ++tau) {
        acc[tau] = __builtin_amdgcn_mfma_f32_16x16x32_bf16(a0, wb0[tau], acc[tau], 0, 0, 0);
        asm volatile("" : "+v"(acc[tau]));   // keep accumulator in VGPRs for cell math
      }

      // cell update: unit j = tu*16 + c lives at tiles {tu, tu+2, tu+4, tu+6} = {i,f,g,o}
#pragma unroll
      for (int tu = 0; tu < 2; ++tu) {
#pragma unroll
        for (int p = 0; p < 2; ++p) {
          f32x2 gi = { acc[tu    ][2*p], acc[tu    ][2*p+1] };
          f32x2 gf = { acc[tu + 2][2*p], acc[tu + 2][2*p+1] };
          f32x2 gg = { acc[tu + 4][2*p], acc[tu + 4][2*p+1] };
          f32x2 go = { acc[tu + 6][2*p], acc[tu + 6][2*p+1] };
          f32x2 hh = cell_pair<false>(gi, gf, gg, go, c0p[tu][p],
                                      1.f, 1.f, 1.f, 1.f, 1.f);
          my0[(q * 4 + 2*p    ) * 40 + tu * 16 + c] = f2bf(hh.x);
          my0[(q * 4 + 2*p + 1) * 40 + tu * 16 + c] = f2bf(hh.y);
        }
      }
      asm volatile("" ::: "memory");
      a0 = *(const bf16x8*)(my0 + c * 40 + q * 8);  // A-frag: A[m=c][k=q*8+j]

      // ---- Layer 1: gates' = sc*b1 (mult-folded) + h0_new @ W' + h1_prev @ W'' ----
#pragma unroll
      for (int tau = 0; tau < 8; ++tau)
        acc[tau] = __builtin_amdgcn_mfma_f32_16x16x32_bf16(a0, wb1[tau], zero4, 0, 0, 0);
#pragma unroll
      for (int tau = 0; tau < 8; ++tau) {
        acc[tau] = __builtin_amdgcn_mfma_f32_16x16x32_bf16(a1, wb2[tau], acc[tau], 0, 0, 0);
        asm volatile("" : "+v"(acc[tau]));   // keep accumulator in VGPRs for cell math
      }

#pragma unroll
      for (int tu = 0; tu < 2; ++tu) {
#pragma unroll
        for (int p = 0; p < 2; ++p) {
          f32x2 gi = { acc[tu    ][2*p], acc[tu    ][2*p+1] };
          f32x2 gf = { acc[tu + 2][2*p], acc[tu + 2][2*p+1] };
          f32x2 gg = { acc[tu + 4][2*p], acc[tu + 4][2*p+1] };
          f32x2 go = { acc[tu + 6][2*p], acc[tu + 6][2*p+1] };
          f32x2 hh = cell_pair<true>(gi, gf, gg, go, c1p[tu][p],
                                     eb1[tu], eb1[tu + 2], eb1[tu + 4],
                                     (tu == 0) ? kng4 : kng5, eb1[tu + 6]);
          my1[(q * 4 + 2*p    ) * 40 + tu * 16 + c] = f2bf(hh.x);
          my1[(q * 4 + 2*p + 1) * 40 + tu * 16 + c] = f2bf(hh.y);
        }
      }
      asm volatile("" ::: "memory");
      a1 = *(const bf16x8*)(my1 + c * 40 + q * 8);
    }
  }

  // ---- Output: out[b, n] = sum_j h1[b][j] * Wfc[n, 0, j] + bfc[n] ----
  // Final h1 read back (bf16) from the LDS buffer this lane's wave wrote:
  // h1[m = q*4 + r][j = tu*16 + c]; reduce over the 16 c-lanes of each quad.
  float h1v[2][4];
#pragma unroll
  for (int tu = 0; tu < 2; ++tu)
#pragma unroll
    for (int r = 0; r < 4; ++r) {
      unsigned short us = (unsigned short)my1[(q * 4 + r) * 40 + tu * 16 + c];
      h1v[tu][r] = __builtin_bit_cast(float, ((unsigned)us) << 16);
    }
  float s0 = h1v[0][0] * wfc0 + h1v[1][0] * wfc1;
  float s1 = h1v[0][1] * wfc0 + h1v[1][1] * wfc1;
  float s2 = h1v[0][2] * wfc0 + h1v[1][2] * wfc1;
  float s3 = h1v[0][3] * wfc0 + h1v[1][3] * wfc1;
#pragma unroll
  for (int off = 1; off < 16; off <<= 1) {
    s0 += __shfl_xor(s0, off, 64);
    s1 += __shfl_xor(s1, off, 64);
    s2 += __shfl_xor(s2, off, 64);
    s3 += __shfl_xor(s3, off, 64);
  }
  if (c < 4) {
    float v = (c == 0) ? s0 : (c == 1) ? s1 : (c == 2) ? s2 : s3;
    out[(size_t)(m0 + q * 4 + c) * NN + n] = v + bfc[n];
  }
}

extern "C" void kernel_launch(void* const* d_in, const int* in_sizes, int n_in,
                              void* d_out, int out_size, void* d_ws, size_t ws_size,
                              hipStream_t stream) {
  const float* x    = (const float*)d_in[0];
  const float* Wih0 = (const float*)d_in[1];
  const float* Whh0 = (const float*)d_in[2];
  const float* b0   = (const float*)d_in[3];
  const float* Wih1 = (const float*)d_in[4];
  const float* Whh1 = (const float*)d_in[5];
  const float* b1   = (const float*)d_in[6];
  const float* Wfc  = (const float*)d_in[7];
  const float* bfc  = (const float*)d_in[8];
  float* out = (float*)d_out;

  lstm_kernel<<<dim3(1024), dim3(256), 0, stream>>>(
      x, Wih0, Whh0, b0, Wih1, Whh1, b1, Wfc, bfc, out);
}

// Round 8
// 1317.508 us; speedup vs baseline: 1.9651x; 1.9651x over previous
//
#include <hip/hip_runtime.h>
#include <stdint.h>

#define NB 512   // batch
#define NN 128   // nodes
#define NT 336   // timesteps
#define NH 32    // hidden
#define NG 128   // 4*H

typedef short bf16x8 __attribute__((ext_vector_type(8)));
typedef float f32x4  __attribute__((ext_vector_type(4)));
typedef float f32x2  __attribute__((ext_vector_type(2)));
typedef float f32v4  __attribute__((ext_vector_type(4)));

#define LOG2E 1.4426950408889634f
#define KNEG  (-2.0f * LOG2E)   // tanh-arg scale, folded into c-state

__device__ __forceinline__ f32x2 exp2v(f32x2 v) {
  f32x2 r; r.x = __builtin_amdgcn_exp2f(v.x); r.y = __builtin_amdgcn_exp2f(v.y); return r;
}
__device__ __forceinline__ f32x2 rcpv(f32x2 v) {
  f32x2 r; r.x = __builtin_amdgcn_rcpf(v.x); r.y = __builtin_amdgcn_rcpf(v.y); return r;
}
// float -> bf16, round-to-nearest (ties away): add + hi16
__device__ __forceinline__ short f2bf(float f) {
  unsigned u = __builtin_bit_cast(unsigned, f) + 0x8000u;
  return (short)(u >> 16);
}

// Fused LSTM cell for a pair of batch rows (packed f32x2).
// Gate pre-activations arrive pre-scaled: i,f,o by -log2e; g by -2log2e.
// c-state is stored SCALED by KNEG (= -2log2e): the tanh exp2-arg IS the state.
//   cS' = [cS*Ai*Au + nuk*Af] / (Af*Ai*Au)   -- single rcp   (nuk = KNEG*(1-u'))
//   h   = (1-v) / (Ao*(1+v)),  v = exp2(min(cS',80))  -- single rcp
// BIAS=true folds bias multiplicatively; kng = -KNEG*ebg precomputed.
template<bool BIAS>
__device__ __forceinline__ f32x2 cell_pair(f32x2 gi, f32x2 gf, f32x2 gg, f32x2 go,
                                           f32x2& cst, float ebi, float ebf,
                                           float ebg, float kng, float ebo) {
  f32x2 wi = exp2v(gi), wf = exp2v(gf), uu = exp2v(gg), wo = exp2v(go);
  f32x2 Ai, Af, Au, Ao, nuk;
  if (BIAS) {
    Ai  = wi * ebi + 1.0f;          // v_pk_fma_f32
    Af  = wf * ebf + 1.0f;
    Au  = uu * ebg + 1.0f;
    Ao  = wo * ebo + 1.0f;
    nuk = uu * kng + KNEG;          // KNEG*(1 - uu*ebg)
  } else {
    Ai  = wi + 1.0f; Af = wf + 1.0f; Au = uu + 1.0f; Ao = wo + 1.0f;
    nuk = uu * (-KNEG) + KNEG;      // KNEG*(1-uu)
  }
  f32x2 P  = Ai * Au;
  f32x2 N  = cst * P + nuk * Af;
  f32x2 cS = N * rcpv(Af * P);      // = KNEG * c_new
  cst = cS;
  f32x2 sarg = cS;
  sarg.x = fminf(sarg.x, 80.0f);    // guard inf/inf NaN; clamp still -> -sigma(o)
  sarg.y = fminf(sarg.y, 80.0f);
  f32x2 vv = exp2v(sarg);
  f32x2 hh = (1.0f - vv) * rcpv(Ao * (vv + 1.0f));
  return hh;
}

// One wave handles (node n, 16 batch rows). Block = 4 waves = 64 rows of one node.
// Grid = 128 nodes * 8 row-groups = 1024 blocks.
// Weights live in LDS (shared by the block's 4 waves) -> ~96 VGPRs freed,
// enabling (256,3). NOTE (256,3) with weights-in-regs spilled (r5, 3.4x slower);
// with weights in LDS the register demand is ~115 so the 170-reg cap is safe.
#define WSTRIDE 40   // weight row stride (elems): 80B rows, 16B-aligned, conflict-free
#define HSTRIDE 32   // h-scratch row stride (elems): b128 frag read is conflict-free
__global__ __launch_bounds__(256, 3) void lstm_kernel(
    const float* __restrict__ x,
    const float* __restrict__ Wih0,
    const float* __restrict__ Whh0,
    const float* __restrict__ b0,
    const float* __restrict__ Wih1,
    const float* __restrict__ Whh1,
    const float* __restrict__ b1,
    const float* __restrict__ Wfc,
    const float* __restrict__ bfc,
    float* __restrict__ out)
{
  const int tid  = threadIdx.x;
  const int wave = tid >> 6;
  const int lane = tid & 63;
  const int c    = lane & 15;   // tile column (gate-within-tile / A-row)
  const int q    = lane >> 4;   // quad
  const int n    = blockIdx.x >> 3;
  const int m0   = ((blockIdx.x & 7) * 4 + wave) * 16;  // batch row base of this wave

  // LDS: 3 weight matrices (scaled, bf16) + per-wave-private h scratch.
  __shared__ short lds_w[3 * NG * WSTRIDE];             // 30720 B
  __shared__ short lds_h[4 * 2 * 16 * HSTRIDE];         //  8192 B
  short* my0 = lds_h + wave * (2 * 16 * HSTRIDE);
  short* my1 = my0 + 16 * HSTRIDE;

  // ---- Cooperative weight staging: W'[g][k] = sc(g) * W[g][k], bf16, stride 40 ----
  // sc: rows 0-63 (i,f) & 96-127 (o): -log2e; rows 64-95 (g): -2log2e.
  {
    const float* srcs[3] = { Whh0 + n * (NG * NH), Wih1 + n * (NG * NH),
                             Whh1 + n * (NG * NH) };
#pragma unroll 1
    for (int idx = tid; idx < 3 * NG * NH; idx += 256) {
      int mat = idx >> 12;          // /4096
      int rem = idx & 4095;
      int row = rem >> 5, col = rem & 31;
      float sc = (row >= 64 && row < 96) ? (-2.0f * LOG2E) : (-LOG2E);
      lds_w[mat * (NG * WSTRIDE) + row * WSTRIDE + col] = f2bf(sc * srcs[mat][rem]);
    }
  }

  // Per-lane gate constants: g = tau*16 + c.
  float b0g[8], eb1[8], wi0g[8];
#pragma unroll
  for (int tau = 0; tau < 8; ++tau) {
    int g = tau * 16 + c;
    float sc = (tau == 4 || tau == 5) ? (-2.0f * LOG2E) : (-LOG2E);
    b0g[tau]  = sc * b0[n * NG + g];
    eb1[tau]  = __builtin_amdgcn_exp2f(sc * b1[n * NG + g]);
    wi0g[tau] = sc * Wih0[n * NG + g];   // W_ih0[n, g, 0]
  }
  const float kng4 = (-KNEG) * eb1[4];
  const float kng5 = (-KNEG) * eb1[5];
  const float wfc0 = Wfc[n * NH + c];
  const float wfc1 = Wfc[n * NH + 16 + c];

  __syncthreads();  // weights visible to all 4 waves; only barrier in the kernel

  // Per-lane weight-fragment base: frag(mat,tau) = wbase + mat*5120 + tau*640 elems.
  // B-frag (K x N = 32 x 16): lane holds B[k=q*8+j][nn=c] = W'[tau*16+c][q*8+j].
  const short* wbase = lds_w + c * WSTRIDE + q * 8;

  // x row pointers for the 4 batch rows this lane's quad covers (m = q*4 + r)
  const float* px0 = x + ((size_t)(m0 + q * 4 + 0) * NN + n) * NT;
  const float* px1 = x + ((size_t)(m0 + q * 4 + 1) * NN + n) * NT;
  const float* px2 = x + ((size_t)(m0 + q * 4 + 2) * NN + n) * NT;
  const float* px3 = x + ((size_t)(m0 + q * 4 + 3) * NN + n) * NT;

  bf16x8 a0 = {0,0,0,0,0,0,0,0};
  bf16x8 a1 = {0,0,0,0,0,0,0,0};
  f32x2 c0p[2][2], c1p[2][2];
#pragma unroll
  for (int tu = 0; tu < 2; ++tu)
#pragma unroll
    for (int p = 0; p < 2; ++p) {
      c0p[tu][p] = (f32x2){0.f, 0.f};
      c1p[tu][p] = (f32x2){0.f, 0.f};
    }

  const f32x4 zero4 = {0.f, 0.f, 0.f, 0.f};

#pragma unroll 1
  for (int t4 = 0; t4 < NT / 4; ++t4) {
    f32v4 xr0 = *(const f32v4*)(px0 + t4 * 4);
    f32v4 xr1 = *(const f32v4*)(px1 + t4 * 4);
    f32v4 xr2 = *(const f32v4*)(px2 + t4 * 4);
    f32v4 xr3 = *(const f32v4*)(px3 + t4 * 4);

#pragma unroll
    for (int ts = 0; ts < 4; ++ts) {
      f32x2 x01 = {xr0[ts], xr1[ts]};
      f32x2 x23 = {xr2[ts], xr3[ts]};

      // ---- Layer 0, split into two tu-groups of 4 tiles (i,f,g,o of 16 units)
      //      -> only 16 acc VGPRs live at once ----
#pragma unroll
      for (int tu = 0; tu < 2; ++tu) {
        f32x4 acc[4];
#pragma unroll
        for (int k = 0; k < 4; ++k) {
          int tau = tu + 2 * k;
          f32x2 w2 = {wi0g[tau], wi0g[tau]};
          f32x2 b2 = {b0g[tau], b0g[tau]};
          f32x2 lo = x01 * w2 + b2;   // v_pk_fma_f32
          f32x2 hi = x23 * w2 + b2;
          acc[k] = (f32x4){lo.x, lo.y, hi.x, hi.y};
        }
#pragma unroll
        for (int k = 0; k < 4; ++k) {
          int tau = tu + 2 * k;
          bf16x8 bw = *(const bf16x8*)(wbase + 0 * (NG * WSTRIDE) + tau * (16 * WSTRIDE));
          acc[k] = __builtin_amdgcn_mfma_f32_16x16x32_bf16(a0, bw, acc[k], 0, 0, 0);
        }
#pragma unroll
        for (int p = 0; p < 2; ++p) {
          f32x2 gi = { acc[0][2*p], acc[0][2*p+1] };
          f32x2 gf = { acc[1][2*p], acc[1][2*p+1] };
          f32x2 gg = { acc[2][2*p], acc[2][2*p+1] };
          f32x2 go = { acc[3][2*p], acc[3][2*p+1] };
          f32x2 hh = cell_pair<false>(gi, gf, gg, go, c0p[tu][p],
                                      1.f, 1.f, 1.f, 1.f, 1.f);
          my0[(q * 4 + 2*p    ) * HSTRIDE + tu * 16 + c] = f2bf(hh.x);
          my0[(q * 4 + 2*p + 1) * HSTRIDE + tu * 16 + c] = f2bf(hh.y);
        }
      }
      asm volatile("" ::: "memory");
      a0 = *(const bf16x8*)(my0 + c * HSTRIDE + q * 8);  // A-frag: A[m=c][k=q*8+j]

      // ---- Layer 1, same tu-split: b1 mult-folded; C = h0@W_ih1' + h1@W_hh1' ----
#pragma unroll
      for (int tu = 0; tu < 2; ++tu) {
        f32x4 acc[4];
#pragma unroll
        for (int k = 0; k < 4; ++k) {
          int tau = tu + 2 * k;
          bf16x8 b1f = *(const bf16x8*)(wbase + 1 * (NG * WSTRIDE) + tau * (16 * WSTRIDE));
          acc[k] = __builtin_amdgcn_mfma_f32_16x16x32_bf16(a0, b1f, zero4, 0, 0, 0);
        }
#pragma unroll
        for (int k = 0; k < 4; ++k) {
          int tau = tu + 2 * k;
          bf16x8 b2f = *(const bf16x8*)(wbase + 2 * (NG * WSTRIDE) + tau * (16 * WSTRIDE));
          acc[k] = __builtin_amdgcn_mfma_f32_16x16x32_bf16(a1, b2f, acc[k], 0, 0, 0);
        }
#pragma unroll
        for (int p = 0; p < 2; ++p) {
          f32x2 gi = { acc[0][2*p], acc[0][2*p+1] };
          f32x2 gf = { acc[1][2*p], acc[1][2*p+1] };
          f32x2 gg = { acc[2][2*p], acc[2][2*p+1] };
          f32x2 go = { acc[3][2*p], acc[3][2*p+1] };
          f32x2 hh = cell_pair<true>(gi, gf, gg, go, c1p[tu][p],
                                     eb1[tu], eb1[tu + 2], eb1[tu + 4],
                                     (tu == 0) ? kng4 : kng5, eb1[tu + 6]);
          my1[(q * 4 + 2*p    ) * HSTRIDE + tu * 16 + c] = f2bf(hh.x);
          my1[(q * 4 + 2*p + 1) * HSTRIDE + tu * 16 + c] = f2bf(hh.y);
        }
      }
      asm volatile("" ::: "memory");
      a1 = *(const bf16x8*)(my1 + c * HSTRIDE + q * 8);
    }
  }

  // ---- Output: out[b, n] = sum_j h1[b][j] * Wfc[n, 0, j] + bfc[n] ----
  // Final h1 read back (bf16) from this wave's private LDS buffer:
  // h1[m = q*4 + r][j = tu*16 + c]; reduce over the 16 c-lanes of each quad.
  float h1v[2][4];
#pragma unroll
  for (int tu = 0; tu < 2; ++tu)
#pragma unroll
    for (int r = 0; r < 4; ++r) {
      unsigned short us = (unsigned short)my1[(q * 4 + r) * HSTRIDE + tu * 16 + c];
      h1v[tu][r] = __builtin_bit_cast(float, ((unsigned)us) << 16);
    }
  float s0 = h1v[0][0] * wfc0 + h1v[1][0] * wfc1;
  float s1 = h1v[0][1] * wfc0 + h1v[1][1] * wfc1;
  float s2 = h1v[0][2] * wfc0 + h1v[1][2] * wfc1;
  float s3 = h1v[0][3] * wfc0 + h1v[1][3] * wfc1;
#pragma unroll
  for (int off = 1; off < 16; off <<= 1) {
    s0 += __shfl_xor(s0, off, 64);
    s1 += __shfl_xor(s1, off, 64);
    s2 += __shfl_xor(s2, off, 64);
    s3 += __shfl_xor(s3, off, 64);
  }
  if (c < 4) {
    float v = (c == 0) ? s0 : (c == 1) ? s1 : (c == 2) ? s2 : s3;
    out[(size_t)(m0 + q * 4 + c) * NN + n] = v + bfc[n];
  }
}

extern "C" void kernel_launch(void* const* d_in, const int* in_sizes, int n_in,
                              void* d_out, int out_size, void* d_ws, size_t ws_size,
                              hipStream_t stream) {
  const float* x    = (const float*)d_in[0];
  const float* Wih0 = (const float*)d_in[1];
  const float* Whh0 = (const float*)d_in[2];
  const float* b0   = (const float*)d_in[3];
  const float* Wih1 = (const float*)d_in[4];
  const float* Whh1 = (const float*)d_in[5];
  const float* b1   = (const float*)d_in[6];
  const float* Wfc  = (const float*)d_in[7];
  const float* bfc  = (const float*)d_in[8];
  float* out = (float*)d_out;

  lstm_kernel<<<dim3(1024), dim3(256), 0, stream>>>(
      x, Wih0, Whh0, b0, Wih1, Whh1, b1, Wfc, bfc, out);
}